// Round 16
// baseline (312.785 us; speedup 1.0000x reference)
//
#include <hip/hip_runtime.h>
#include <math.h>

#define BN_   2048
#define INDIM 1024
#define HD    256
#define OD    512
#define TN    12
#define KN    3
#define NHOPS 4
#define TP1   13

#define ER    8              // expert/gemm row tile
#define CR    16             // comb row tile

// async global -> LDS, 16B per lane (LDS dest linear in tid)
__device__ __forceinline__ void gll16(const float* g, float* l) {
  __builtin_amdgcn_global_load_lds(
      (const __attribute__((address_space(1))) void*)g,
      (__attribute__((address_space(3))) void*)l, 16, 0, 0);
}

__device__ __forceinline__ float4 ld4(const float* p) { return *(const float4*)p; }

__device__ __forceinline__ void fma4(float4& c, float a, const float4 b) {
  c.x = fmaf(a, b.x, c.x); c.y = fmaf(a, b.y, c.y);
  c.z = fmaf(a, b.z, c.z); c.w = fmaf(a, b.w, c.w);
}
__device__ __forceinline__ void add4(float4& c, const float4 b) {
  c.x += b.x; c.y += b.y; c.z += b.z; c.w += b.w;
}

// ---- (dense GEMM helper) barrier-free K loop, 2-deep W prefetch, 4 cols/lane ----
template<int NR>
__device__ __forceinline__ void kloop2(float4* acc, const float* SA, int astr,
                                       const float* w0, int ws, int nk4, int ks0) {
  const float* wp = w0;
  float4 a0 = ld4(wp),          a1 = ld4(wp + ws),
         a2 = ld4(wp + 2 * ws), a3 = ld4(wp + 3 * ws);
  float4 b0 = ld4(wp + 4 * ws), b1 = ld4(wp + 5 * ws),
         b2 = ld4(wp + 6 * ws), b3 = ld4(wp + 7 * ws);
#pragma unroll 1
  for (int k4 = 0; k4 < nk4 - 2; k4 += 2) {
    float4 c0 = ld4(wp + 8 * ws),  c1 = ld4(wp + 9 * ws),
           c2 = ld4(wp + 10 * ws), c3 = ld4(wp + 11 * ws);
    const int kk = ks0 + k4 * 4;
#pragma unroll
    for (int r = 0; r < NR; ++r) {
      float4 av = *(const float4*)(SA + r * astr + kk);
      fma4(acc[r], av.x, a0); fma4(acc[r], av.y, a1);
      fma4(acc[r], av.z, a2); fma4(acc[r], av.w, a3);
    }
    float4 d0 = ld4(wp + 12 * ws), d1 = ld4(wp + 13 * ws),
           d2 = ld4(wp + 14 * ws), d3 = ld4(wp + 15 * ws);
#pragma unroll
    for (int r = 0; r < NR; ++r) {
      float4 av = *(const float4*)(SA + r * astr + kk + 4);
      fma4(acc[r], av.x, b0); fma4(acc[r], av.y, b1);
      fma4(acc[r], av.z, b2); fma4(acc[r], av.w, b3);
    }
    a0 = c0; a1 = c1; a2 = c2; a3 = c3;
    b0 = d0; b1 = d1; b2 = d2; b3 = d3;
    wp += 8 * ws;
  }
  const int kk = ks0 + (nk4 - 2) * 4;
#pragma unroll
  for (int r = 0; r < NR; ++r) {
    float4 av = *(const float4*)(SA + r * astr + kk);
    fma4(acc[r], av.x, a0); fma4(acc[r], av.y, a1);
    fma4(acc[r], av.z, a2); fma4(acc[r], av.w, a3);
  }
#pragma unroll
  for (int r = 0; r < NR; ++r) {
    float4 av = *(const float4*)(SA + r * astr + kk + 4);
    fma4(acc[r], av.x, b0); fma4(acc[r], av.y, b1);
    fma4(acc[r], av.z, b2); fma4(acc[r], av.w, b3);
  }
}

// ---- (dense GEMM helper) deterministic 4-wave reduction ----
template<int NR>
__device__ __forceinline__ void reduce4(float4* acc, float4 (*pbA)[64],
                                        float4 (*pbB)[64], int w, int tx) {
  __syncthreads();
  if (w == 1) {
#pragma unroll
    for (int r = 0; r < NR; ++r) pbA[r][tx] = acc[r];
  } else if (w == 3) {
#pragma unroll
    for (int r = 0; r < NR; ++r) pbB[r][tx] = acc[r];
  }
  __syncthreads();
  if (w == 0) {
#pragma unroll
    for (int r = 0; r < NR; ++r) add4(acc[r], pbA[r][tx]);
  } else if (w == 2) {
#pragma unroll
    for (int r = 0; r < NR; ++r) add4(acc[r], pbB[r][tx]);
  }
  __syncthreads();
  if (w == 2) {
#pragma unroll
    for (int r = 0; r < NR; ++r) pbA[r][tx] = acc[r];
  }
  __syncthreads();
  if (w == 0) {
#pragma unroll
    for (int r = 0; r < NR; ++r) add4(acc[r], pbA[r][tx]);
  }
}

// ---- (expert) half-wave K loop, 8 cols/lane, 2-deep W prefetch ----
// lane owns cols {cg*4..+3, 128+cg*4..+3}; k-range kb..kb+32 (8 windows of 4k).
// A broadcast b128 (wave-uniform addr); per k4-step: 512cy FMA vs 96cy LDS.
__device__ __forceinline__ void kloop_hw2(float4 (*acc)[2], const float* SA,
                                          const float* W0, int kb, int cg) {
  const float* wp = W0 + (size_t)kb * HD + cg * 4;
  float4 pa[8], pb[8];
#pragma unroll
  for (int j = 0; j < 4; ++j) { pa[j] = ld4(wp + j * HD); pa[4 + j] = ld4(wp + j * HD + 128); }
#pragma unroll
  for (int j = 0; j < 4; ++j) { pb[j] = ld4(wp + (4 + j) * HD); pb[4 + j] = ld4(wp + (4 + j) * HD + 128); }
#pragma unroll 1
  for (int k4 = 0; k4 < 6; k4 += 2) {
    float4 pc[8];
#pragma unroll
    for (int j = 0; j < 4; ++j) { pc[j] = ld4(wp + (8 + j) * HD); pc[4 + j] = ld4(wp + (8 + j) * HD + 128); }
    int kk = kb + k4 * 4;
#pragma unroll
    for (int r = 0; r < ER; ++r) {
      float4 av = *(const float4*)(SA + r * HD + kk);
      fma4(acc[r][0], av.x, pa[0]); fma4(acc[r][1], av.x, pa[4]);
      fma4(acc[r][0], av.y, pa[1]); fma4(acc[r][1], av.y, pa[5]);
      fma4(acc[r][0], av.z, pa[2]); fma4(acc[r][1], av.z, pa[6]);
      fma4(acc[r][0], av.w, pa[3]); fma4(acc[r][1], av.w, pa[7]);
    }
    float4 pd[8];
#pragma unroll
    for (int j = 0; j < 4; ++j) { pd[j] = ld4(wp + (12 + j) * HD); pd[4 + j] = ld4(wp + (12 + j) * HD + 128); }
#pragma unroll
    for (int r = 0; r < ER; ++r) {
      float4 av = *(const float4*)(SA + r * HD + kk + 4);
      fma4(acc[r][0], av.x, pb[0]); fma4(acc[r][1], av.x, pb[4]);
      fma4(acc[r][0], av.y, pb[1]); fma4(acc[r][1], av.y, pb[5]);
      fma4(acc[r][0], av.z, pb[2]); fma4(acc[r][1], av.z, pb[6]);
      fma4(acc[r][0], av.w, pb[3]); fma4(acc[r][1], av.w, pb[7]);
    }
#pragma unroll
    for (int j = 0; j < 8; ++j) { pa[j] = pc[j]; pb[j] = pd[j]; }
    wp += 8 * HD;
  }
  int kk = kb + 24;
#pragma unroll
  for (int r = 0; r < ER; ++r) {
    float4 av = *(const float4*)(SA + r * HD + kk);
    fma4(acc[r][0], av.x, pa[0]); fma4(acc[r][1], av.x, pa[4]);
    fma4(acc[r][0], av.y, pa[1]); fma4(acc[r][1], av.y, pa[5]);
    fma4(acc[r][0], av.z, pa[2]); fma4(acc[r][1], av.z, pa[6]);
    fma4(acc[r][0], av.w, pa[3]); fma4(acc[r][1], av.w, pa[7]);
  }
#pragma unroll
  for (int r = 0; r < ER; ++r) {
    float4 av = *(const float4*)(SA + r * HD + kk + 4);
    fma4(acc[r][0], av.x, pb[0]); fma4(acc[r][1], av.x, pb[4]);
    fma4(acc[r][0], av.y, pb[1]); fma4(acc[r][1], av.y, pb[5]);
    fma4(acc[r][0], av.z, pb[2]); fma4(acc[r][1], av.z, pb[6]);
    fma4(acc[r][0], av.w, pb[3]); fma4(acc[r][1], av.w, pb[7]);
  }
}

// ---- (expert) deterministic 8-partial reduction (4 waves x 2 halves) ----
// conflict-free: lane cg stores float4s at [cg] and [cg+32]. final sum in (w0,hw0).
__device__ __forceinline__ void reduce8h(float4 (*acc)[2],
    float4 (*pbA)[64], float4 (*pbB)[64], float4 (*pbC)[64], float4 (*pbD)[64],
    int w, int hw, int cg) {
  __syncthreads();                         // kloop LDS reads done (sA/sH reuse safe)
  if (hw == 1) {
    float4 (*dst)[64] = (w == 0) ? pbA : (w == 1) ? pbB : (w == 2) ? pbC : pbD;
#pragma unroll
    for (int r = 0; r < ER; ++r) { dst[r][cg] = acc[r][0]; dst[r][cg + 32] = acc[r][1]; }
  }
  __syncthreads();
  if (hw == 0) {
    float4 (*src)[64] = (w == 0) ? pbA : (w == 1) ? pbB : (w == 2) ? pbC : pbD;
#pragma unroll
    for (int r = 0; r < ER; ++r) { add4(acc[r][0], src[r][cg]); add4(acc[r][1], src[r][cg + 32]); }
  }
  __syncthreads();
  if (hw == 0 && (w == 1 || w == 3)) {
    float4 (*dst)[64] = (w == 1) ? pbA : pbB;
#pragma unroll
    for (int r = 0; r < ER; ++r) { dst[r][cg] = acc[r][0]; dst[r][cg + 32] = acc[r][1]; }
  }
  __syncthreads();
  if (hw == 0 && (w == 0 || w == 2)) {
    float4 (*src)[64] = (w == 0) ? pbA : pbB;
#pragma unroll
    for (int r = 0; r < ER; ++r) { add4(acc[r][0], src[r][cg]); add4(acc[r][1], src[r][cg + 32]); }
  }
  __syncthreads();
  if (hw == 0 && w == 2) {
#pragma unroll
    for (int r = 0; r < ER; ++r) { pbA[r][cg] = acc[r][0]; pbA[r][cg + 32] = acc[r][1]; }
  }
  __syncthreads();
  if (hw == 0 && w == 0) {
#pragma unroll
    for (int r = 0; r < ER; ++r) { add4(acc[r][0], pbA[r][cg]); add4(acc[r][1], pbA[r][cg + 32]); }
  }
}

// ---------------- init: zero counters + build hop-0 grouping (single block) ----------------
__global__ __launch_bounds__(1024) void k_init(const int* __restrict__ init_t,
                                               int* __restrict__ cnt,
                                               int* __restrict__ gidx) {
  const int tid = threadIdx.x;
  if (tid < NHOPS * 16) cnt[tid] = 0;
  __syncthreads();
  for (int n = tid; n < BN_; n += 1024) {
    int t = init_t[n];
    int slot = atomicAdd(&cnt[t], 1);
    gidx[t * BN_ + slot] = n;
  }
}

// ---------------- gemm_in partial: pp[kh] = x[:, kh*512:+512] @ W_in[kh*512:+512, :] ----------------
__global__ __launch_bounds__(256) void k_gemm_in(const float* __restrict__ A,
                                                 const float* __restrict__ W,
                                                 float* __restrict__ pp) {
  const int bm = blockIdx.x * ER;
  const int kh = blockIdx.y;
  __shared__ __align__(16) float sA[ER][512];
  __shared__ float4 pbA[ER][64];
  __shared__ float4 pbB[ER][64];
  const int tid = threadIdx.x;
  const int tx = tid & 63;
  const int w = tid >> 6;

#pragma unroll
  for (int l = 0; l < 4; ++l) {
    int idx = tid + l * 256;
    int r = idx >> 7;                  // wave-uniform
    int c = (idx & 127) << 2;
    gll16(&A[(size_t)(bm + r) * INDIM + kh * 512 + c], &sA[r][c]);
  }
  __syncthreads();

  float4 acc[ER];
#pragma unroll
  for (int r = 0; r < ER; ++r) acc[r] = make_float4(0.f, 0.f, 0.f, 0.f);

  const int ks = w * 128;
  kloop2<ER>(acc, &sA[0][0], 512, W + (size_t)(kh * 512 + ks) * HD + tx * 4, HD, 32, ks);
  reduce4<ER>(acc, pbA, pbB, w, tx);

  if (w == 0) {
#pragma unroll
    for (int r = 0; r < ER; ++r)
      *(float4*)&pp[((size_t)kh * BN_ + bm + r) * HD + tx * 4] = acc[r];
  }
}

// ---------------- combine gemm_in partials + bias ----------------
__global__ __launch_bounds__(256) void k_cin(const float* __restrict__ pp,
                                             const float* __restrict__ bias,
                                             float* __restrict__ states) {
  int idx = blockIdx.x * 256 + threadIdx.x;     // float4 index
  int c = (idx & 63) << 2;
  float4 a = ld4(&pp[(size_t)idx * 4]);
  float4 b = ld4(&pp[(size_t)BN_ * HD + (size_t)idx * 4]);
  float4 bv = ld4(&bias[c]);
  float4 o = make_float4(a.x + b.x + bv.x, a.y + b.y + bv.y,
                         a.z + b.z + bv.z, a.w + b.w + bv.w);
  *(float4*)&states[(size_t)idx * 4] = o;
}

// ---------------- gemm_out: out = states @ W_out + b_out ----------------
__global__ __launch_bounds__(256) void k_gemm_out(const float* __restrict__ A,
                                                  const float* __restrict__ W,
                                                  const float* __restrict__ bias,
                                                  float* __restrict__ C) {
  const int bm = blockIdx.x * ER;
  const int cb = blockIdx.y * 256;
  __shared__ __align__(16) float sA[ER][HD];
  __shared__ float4 pbA[ER][64];
  __shared__ float4 pbB[ER][64];
  const int tid = threadIdx.x;
  const int tx = tid & 63;
  const int w = tid >> 6;

#pragma unroll
  for (int l = 0; l < 2; ++l) {
    int idx = tid + l * 256;
    int r = idx >> 6;                  // wave-uniform (w + 4l)
    int c = (idx & 63) << 2;
    gll16(&A[(size_t)(bm + r) * HD + c], &sA[r][c]);
  }
  __syncthreads();

  float4 acc[ER];
#pragma unroll
  for (int r = 0; r < ER; ++r) acc[r] = make_float4(0.f, 0.f, 0.f, 0.f);

  const int ks = w * 64;
  kloop2<ER>(acc, &sA[0][0], HD, W + (size_t)ks * OD + cb + tx * 4, OD, 16, ks);
  reduce4<ER>(acc, pbA, pbB, w, tx);

  if (w == 0) {
    float4 bv = ld4(&bias[cb + tx * 4]);
#pragma unroll
    for (int r = 0; r < ER; ++r) {
      float4 o = make_float4(acc[r].x + bv.x, acc[r].y + bv.y,
                             acc[r].z + bv.z, acc[r].w + bv.w);
      *(float4*)&C[(size_t)(bm + r) * OD + cb + tx * 4] = o;
    }
  }
}

// ---------------- fused expert: part_k[n] = wk*relu(relu(S@W1+b1)@W2+b2) ----------------
// XCD-balanced decode (24 half-temper units, 3/XCD); 256 thr = 4 waves x 2 halves;
// lane owns 8 cols, half-wave k-split (32 k per half), 2-deep W prefetch.
// grid.x = 8 * 3 * 3 * 128 = 9216.
__global__ __launch_bounds__(256) void k_h1h2(
    int hop,
    const float* __restrict__ W1, const float* __restrict__ b1,
    const float* __restrict__ W2, const float* __restrict__ b2,
    const float* __restrict__ op_noise,
    const int* __restrict__ cnt, const int* __restrict__ gidx,
    const float* __restrict__ states, float* __restrict__ part) {
  const int bid = blockIdx.x;
  const int xcd = bid & 7;
  const int s   = bid >> 3;            // [0,1152)
  const int u   = xcd * 3 + (s % 3);   // unit [0,24)
  const int inner = s / 3;             // [0,384)
  const int k   = inner % 3;
  const int j   = inner / 3;           // [0,128)
  const int t   = u >> 1;
  const int uh  = u & 1;
  const int rb  = j * 2 + uh;          // rowblock [0,256)

  const int cntv = cnt[hop * 16 + t];
  const int r0 = rb * ER;
  if (r0 >= cntv) return;
  const int gb = (hop * TN + t) * BN_ + r0;
  const int rows = min(ER, cntv - r0);

  __shared__ __align__(16) float sA[ER][HD];   // 8KB states rows (scratch pbC in reduce)
  __shared__ __align__(16) float sH[ER][HD];   // 8KB h1 (scratch pbD in reduce)
  __shared__ float4 pbA[ER][64];               // 8KB
  __shared__ float4 pbB[ER][64];               // 8KB  -> 32KB total
  const int tid = threadIdx.x;
  const int w  = tid >> 6;             // wave
  const int hw = (tid >> 5) & 1;       // half-wave
  const int cg = tid & 31;             // col group: cols cg*4..+3 and 128+cg*4..+3
  const int kb = w * 64 + hw * 32;     // lane k-base
  float4 (*pbC)[64] = (float4 (*)[64])sA;
  float4 (*pbD)[64] = (float4 (*)[64])sH;

  // gather active rows (wave-uniform r; tail rows stale -> discarded)
#pragma unroll
  for (int l = 0; l < 2; ++l) {
    int r = w + 4 * l;
    int c = (tid & 63) << 2;
    if (r < rows)
      gll16(&states[(size_t)gidx[gb + r] * HD + c], &sA[r][c]);
  }
  __syncthreads();

  const float* Wa = W1 + (size_t)(t * KN + k) * HD * HD;
  const float* Wb = W2 + (size_t)(t * KN + k) * HD * HD;

  float4 acc[ER][2];
#pragma unroll
  for (int r = 0; r < ER; ++r) {
    acc[r][0] = make_float4(0.f, 0.f, 0.f, 0.f);
    acc[r][1] = make_float4(0.f, 0.f, 0.f, 0.f);
  }

  // ---- layer 1 ----
  kloop_hw2(acc, &sA[0][0], Wa, kb, cg);
  reduce8h(acc, pbA, pbB, pbC, pbD, w, hw, cg);

  if (w == 0 && hw == 0) {
    const float* ba = b1 + (t * KN + k) * HD;
    float4 bv0 = ld4(ba + cg * 4);
    float4 bv1 = ld4(ba + 128 + cg * 4);
#pragma unroll
    for (int r = 0; r < ER; ++r) {
      float4 h0, h1v;
      h0.x = fmaxf(acc[r][0].x + bv0.x, 0.f);
      h0.y = fmaxf(acc[r][0].y + bv0.y, 0.f);
      h0.z = fmaxf(acc[r][0].z + bv0.z, 0.f);
      h0.w = fmaxf(acc[r][0].w + bv0.w, 0.f);
      h1v.x = fmaxf(acc[r][1].x + bv1.x, 0.f);
      h1v.y = fmaxf(acc[r][1].y + bv1.y, 0.f);
      h1v.z = fmaxf(acc[r][1].z + bv1.z, 0.f);
      h1v.w = fmaxf(acc[r][1].w + bv1.w, 0.f);
      *(float4*)&sH[r][cg * 4]       = h0;
      *(float4*)&sH[r][128 + cg * 4] = h1v;
    }
  }
  __syncthreads();

  // ---- layer 2 ----
#pragma unroll
  for (int r = 0; r < ER; ++r) {
    acc[r][0] = make_float4(0.f, 0.f, 0.f, 0.f);
    acc[r][1] = make_float4(0.f, 0.f, 0.f, 0.f);
  }
  kloop_hw2(acc, &sH[0][0], Wb, kb, cg);
  reduce8h(acc, pbA, pbB, pbC, pbD, w, hw, cg);

  if (w == 0 && hw == 0) {
    float wkk;
    {
      const float* on = op_noise + (hop * TN + t) * KN;
      float x0 = on[0], x1 = on[1], x2 = on[2];
      float m = fmaxf(fmaxf(x0, x1), x2);
      float e0 = expf(x0 - m), e1 = expf(x1 - m), e2 = expf(x2 - m);
      float ek = (k == 0) ? e0 : (k == 1) ? e1 : e2;
      wkk = ek / (e0 + e1 + e2);
    }
    const float* bb = b2 + (t * KN + k) * HD;
    float4 bv0 = ld4(bb + cg * 4);
    float4 bv1 = ld4(bb + 128 + cg * 4);
#pragma unroll
    for (int r = 0; r < ER; ++r) {
      if (r < rows) {
        int n = gidx[gb + r];
        float4 o0, o1;
        o0.x = wkk * fmaxf(acc[r][0].x + bv0.x, 0.f);
        o0.y = wkk * fmaxf(acc[r][0].y + bv0.y, 0.f);
        o0.z = wkk * fmaxf(acc[r][0].z + bv0.z, 0.f);
        o0.w = wkk * fmaxf(acc[r][0].w + bv0.w, 0.f);
        o1.x = wkk * fmaxf(acc[r][1].x + bv1.x, 0.f);
        o1.y = wkk * fmaxf(acc[r][1].y + bv1.y, 0.f);
        o1.z = wkk * fmaxf(acc[r][1].z + bv1.z, 0.f);
        o1.w = wkk * fmaxf(acc[r][1].w + bv1.w, 0.f);
        *(float4*)&part[((size_t)k * BN_ + n) * HD + cg * 4]       = o0;
        *(float4*)&part[((size_t)k * BN_ + n) * HD + 128 + cg * 4] = o1;
      }
    }
  }
}

// ---------------- combine partials + routing + Gumbel argmax + regroup ----------------
__global__ __launch_bounds__(256) void k_comb(
    int hop,
    const float* __restrict__ Wr, const float* __restrict__ br,
    const float* __restrict__ route_u,
    int* __restrict__ cnt, int* __restrict__ gidx,
    const float* __restrict__ part,
    float* __restrict__ states) {
  const int t  = blockIdx.x % TN;
  const int rb = blockIdx.x / TN;
  const int cntv = cnt[hop * 16 + t];
  const int r0 = rb * CR;
  if (r0 >= cntv) return;
  const int gb = (hop * TN + t) * BN_ + r0;
  const int rows = min(CR, cntv - r0);

  __shared__ float sO[CR][HD + 4];
  __shared__ float sWr[HD * TP1];
  __shared__ float sL[CR][16];
  __shared__ int   sN[CR];

  const int tid = threadIdx.x;
  if (tid < CR && tid < rows) sN[tid] = gidx[gb + tid];

#pragma unroll
  for (int l = 0; l < 4; ++l) {
    int idx = tid + l * 256;
    int r = idx >> 6;
    int c = (idx & 63) << 2;
    if (r < rows) {
      int n = gidx[gb + r];
      size_t p = (size_t)n * HD + c;
      float4 a = ld4(&part[p]);
      float4 b = ld4(&part[(size_t)BN_ * HD + p]);
      float4 cc = ld4(&part[(size_t)2 * BN_ * HD + p]);
      float4 v = make_float4(a.x + b.x + cc.x, a.y + b.y + cc.y,
                             a.z + b.z + cc.z, a.w + b.w + cc.w);
      *(float4*)&sO[r][c] = v;
      *(float4*)&states[(size_t)n * HD + c] = v;
    }
  }
  for (int i = tid; i < HD * TP1; i += 256)
    sWr[i] = Wr[(size_t)t * HD * TP1 + i];
  __syncthreads();

  int r = tid >> 4, g = tid & 15;
  if (r < rows && g < TP1) {
    float a = br[t * TP1 + g];
#pragma unroll 8
    for (int f = 0; f < HD; ++f) a = fmaf(sO[r][f], sWr[f * TP1 + g], a);
    float u = route_u[((size_t)hop * BN_ + sN[r]) * TP1 + g];
    float gb_ = -logf(-logf(u + 1e-9f) + 1e-9f);
    sL[r][g] = a + gb_;
  }
  __syncthreads();

  if (tid < rows) {
    float best = sL[tid][0];
    int bj = 0;
#pragma unroll
    for (int gg = 1; gg < TP1; ++gg) {
      float v = sL[tid][gg];
      if (v > best) { best = v; bj = gg; }
    }
    if (hop + 1 < NHOPS && bj != TN) {
      int n = sN[tid];
      int slot = atomicAdd(&cnt[(hop + 1) * 16 + bj], 1);
      gidx[((hop + 1) * TN + bj) * BN_ + slot] = n;
    }
  }
}

// ---------------- launcher ----------------
extern "C" void kernel_launch(void* const* d_in, const int* in_sizes, int n_in,
                              void* d_out, int out_size, void* d_ws, size_t ws_size,
                              hipStream_t stream) {
  const float* x        = (const float*)d_in[0];
  const int*   init_t   = (const int*)d_in[1];
  const float* op_noise = (const float*)d_in[2];
  const float* route_u  = (const float*)d_in[3];
  const float* W_in     = (const float*)d_in[4];
  const float* b_in     = (const float*)d_in[5];
  const float* W1       = (const float*)d_in[6];
  const float* b1       = (const float*)d_in[7];
  const float* W2       = (const float*)d_in[8];
  const float* b2       = (const float*)d_in[9];
  const float* Wr       = (const float*)d_in[10];
  const float* br       = (const float*)d_in[11];
  const float* W_out    = (const float*)d_in[12];
  const float* b_out    = (const float*)d_in[13];
  float* out = (float*)d_out;

  float* states = (float*)d_ws;                       // 2MB
  float* part   = states + (size_t)BN_ * HD;          // [KN][BN_][HD] 6MB
  float* pp     = part;                               // gemm_in partials alias (4MB)
  int* cnt  = (int*)(part + (size_t)KN * BN_ * HD);   // [NHOPS][16]
  int* gidx = cnt + NHOPS * 16;                       // [NHOPS][TN][BN_]

  k_init<<<1, 1024, 0, stream>>>(init_t, cnt, gidx);

  k_gemm_in<<<dim3(BN_ / ER, 2), 256, 0, stream>>>(x, W_in, pp);
  k_cin<<<(BN_ * HD / 4) / 256, 256, 0, stream>>>(pp, b_in, states);

  for (int hop = 0; hop < NHOPS; ++hop) {
    k_h1h2<<<8 * 3 * 3 * 128, 256, 0, stream>>>(
        hop, W1, b1, W2, b2, op_noise, cnt, gidx, states, part);
    k_comb<<<TN * (BN_ / CR), 256, 0, stream>>>(
        hop, Wr, br, route_u, cnt, gidx, part, states);
  }

  k_gemm_out<<<dim3(BN_ / ER, OD / 256), 256, 0, stream>>>(states, W_out, b_out, out);
}

// Round 17
// 221.692 us; speedup vs baseline: 1.4109x; 1.4109x over previous
//
#include <hip/hip_runtime.h>
#include <math.h>

#define BN_   2048
#define INDIM 1024
#define HD    256
#define OD    512
#define TN    12
#define KN    3
#define NHOPS 4
#define TP1   13

#define ER    8              // expert/gemm row tile
#define CR    16             // comb row tile

// async global -> LDS, 16B per lane (LDS dest linear in tid)
__device__ __forceinline__ void gll16(const float* g, float* l) {
  __builtin_amdgcn_global_load_lds(
      (const __attribute__((address_space(1))) void*)g,
      (__attribute__((address_space(3))) void*)l, 16, 0, 0);
}

__device__ __forceinline__ float4 ld4(const float* p) { return *(const float4*)p; }

__device__ __forceinline__ void fma4(float4& c, float a, const float4 b) {
  c.x = fmaf(a, b.x, c.x); c.y = fmaf(a, b.y, c.y);
  c.z = fmaf(a, b.z, c.z); c.w = fmaf(a, b.w, c.w);
}
__device__ __forceinline__ void add4(float4& c, const float4 b) {
  c.x += b.x; c.y += b.y; c.z += b.z; c.w += b.w;
}

// ---- barrier-free K loop, 2-deep W prefetch (8 dwordx4 in flight) ----
// acc[NR] += A[NR rows x k-slice] @ W[k-slice x 4 cols]; nk4 even >= 4.
template<int NR>
__device__ __forceinline__ void kloop2(float4* acc, const float* SA, int astr,
                                       const float* w0, int ws, int nk4, int ks0) {
  const float* wp = w0;
  float4 a0 = ld4(wp),          a1 = ld4(wp + ws),
         a2 = ld4(wp + 2 * ws), a3 = ld4(wp + 3 * ws);
  float4 b0 = ld4(wp + 4 * ws), b1 = ld4(wp + 5 * ws),
         b2 = ld4(wp + 6 * ws), b3 = ld4(wp + 7 * ws);
#pragma unroll 1
  for (int k4 = 0; k4 < nk4 - 2; k4 += 2) {
    float4 c0 = ld4(wp + 8 * ws),  c1 = ld4(wp + 9 * ws),
           c2 = ld4(wp + 10 * ws), c3 = ld4(wp + 11 * ws);
    const int kk = ks0 + k4 * 4;
#pragma unroll
    for (int r = 0; r < NR; ++r) {
      float4 av = *(const float4*)(SA + r * astr + kk);
      fma4(acc[r], av.x, a0); fma4(acc[r], av.y, a1);
      fma4(acc[r], av.z, a2); fma4(acc[r], av.w, a3);
    }
    float4 d0 = ld4(wp + 12 * ws), d1 = ld4(wp + 13 * ws),
           d2 = ld4(wp + 14 * ws), d3 = ld4(wp + 15 * ws);
#pragma unroll
    for (int r = 0; r < NR; ++r) {
      float4 av = *(const float4*)(SA + r * astr + kk + 4);
      fma4(acc[r], av.x, b0); fma4(acc[r], av.y, b1);
      fma4(acc[r], av.z, b2); fma4(acc[r], av.w, b3);
    }
    a0 = c0; a1 = c1; a2 = c2; a3 = c3;
    b0 = d0; b1 = d1; b2 = d2; b3 = d3;
    wp += 8 * ws;
  }
  const int kk = ks0 + (nk4 - 2) * 4;
#pragma unroll
  for (int r = 0; r < NR; ++r) {
    float4 av = *(const float4*)(SA + r * astr + kk);
    fma4(acc[r], av.x, a0); fma4(acc[r], av.y, a1);
    fma4(acc[r], av.z, a2); fma4(acc[r], av.w, a3);
  }
#pragma unroll
  for (int r = 0; r < NR; ++r) {
    float4 av = *(const float4*)(SA + r * astr + kk + 4);
    fma4(acc[r], av.x, b0); fma4(acc[r], av.y, b1);
    fma4(acc[r], av.z, b2); fma4(acc[r], av.w, b3);
  }
}

// ---- deterministic 4-wave reduction, fixed association (0+1)+(2+3) ----
template<int NR>
__device__ __forceinline__ void reduce4(float4* acc, float4 (*pbA)[64],
                                        float4 (*pbB)[64], int w, int tx) {
  __syncthreads();
  if (w == 1) {
#pragma unroll
    for (int r = 0; r < NR; ++r) pbA[r][tx] = acc[r];
  } else if (w == 3) {
#pragma unroll
    for (int r = 0; r < NR; ++r) pbB[r][tx] = acc[r];
  }
  __syncthreads();
  if (w == 0) {
#pragma unroll
    for (int r = 0; r < NR; ++r) add4(acc[r], pbA[r][tx]);
  } else if (w == 2) {
#pragma unroll
    for (int r = 0; r < NR; ++r) add4(acc[r], pbB[r][tx]);
  }
  __syncthreads();
  if (w == 2) {
#pragma unroll
    for (int r = 0; r < NR; ++r) pbA[r][tx] = acc[r];
  }
  __syncthreads();
  if (w == 0) {
#pragma unroll
    for (int r = 0; r < NR; ++r) add4(acc[r], pbA[r][tx]);
  }
}

// ---------------- init: zero counters + build hop-0 grouping (single block) ----------------
__global__ __launch_bounds__(1024) void k_init(const int* __restrict__ init_t,
                                               int* __restrict__ cnt,
                                               int* __restrict__ gidx) {
  const int tid = threadIdx.x;
  if (tid < NHOPS * 16) cnt[tid] = 0;
  __syncthreads();
  for (int n = tid; n < BN_; n += 1024) {
    int t = init_t[n];
    int slot = atomicAdd(&cnt[t], 1);
    gidx[t * BN_ + slot] = n;
  }
}

// ---------------- gemm_in partial: pp[kh] = x[:, kh*512:+512] @ W_in[kh*512:+512, :] ----------------
__global__ __launch_bounds__(256) void k_gemm_in(const float* __restrict__ A,
                                                 const float* __restrict__ W,
                                                 float* __restrict__ pp) {
  const int bm = blockIdx.x * ER;
  const int kh = blockIdx.y;
  __shared__ __align__(16) float sA[ER][512];
  __shared__ float4 pbA[ER][64];
  __shared__ float4 pbB[ER][64];
  const int tid = threadIdx.x;
  const int tx = tid & 63;
  const int w = tid >> 6;

#pragma unroll
  for (int l = 0; l < 4; ++l) {
    int idx = tid + l * 256;
    int r = idx >> 7;                  // wave-uniform
    int c = (idx & 127) << 2;
    gll16(&A[(size_t)(bm + r) * INDIM + kh * 512 + c], &sA[r][c]);
  }
  __syncthreads();

  float4 acc[ER];
#pragma unroll
  for (int r = 0; r < ER; ++r) acc[r] = make_float4(0.f, 0.f, 0.f, 0.f);

  const int ks = w * 128;
  kloop2<ER>(acc, &sA[0][0], 512, W + (size_t)(kh * 512 + ks) * HD + tx * 4, HD, 32, ks);
  reduce4<ER>(acc, pbA, pbB, w, tx);

  if (w == 0) {
#pragma unroll
    for (int r = 0; r < ER; ++r)
      *(float4*)&pp[((size_t)kh * BN_ + bm + r) * HD + tx * 4] = acc[r];
  }
}

// ---------------- combine gemm_in partials + bias ----------------
__global__ __launch_bounds__(256) void k_cin(const float* __restrict__ pp,
                                             const float* __restrict__ bias,
                                             float* __restrict__ states) {
  int idx = blockIdx.x * 256 + threadIdx.x;     // float4 index
  int c = (idx & 63) << 2;
  float4 a = ld4(&pp[(size_t)idx * 4]);
  float4 b = ld4(&pp[(size_t)BN_ * HD + (size_t)idx * 4]);
  float4 bv = ld4(&bias[c]);
  float4 o = make_float4(a.x + b.x + bv.x, a.y + b.y + bv.y,
                         a.z + b.z + bv.z, a.w + b.w + bv.w);
  *(float4*)&states[(size_t)idx * 4] = o;
}

// ---------------- gemm_out: out = states @ W_out + b_out ----------------
__global__ __launch_bounds__(256) void k_gemm_out(const float* __restrict__ A,
                                                  const float* __restrict__ W,
                                                  const float* __restrict__ bias,
                                                  float* __restrict__ C) {
  const int bm = blockIdx.x * ER;
  const int cb = blockIdx.y * 256;
  __shared__ __align__(16) float sA[ER][HD];
  __shared__ float4 pbA[ER][64];
  __shared__ float4 pbB[ER][64];
  const int tid = threadIdx.x;
  const int tx = tid & 63;
  const int w = tid >> 6;

#pragma unroll
  for (int l = 0; l < 2; ++l) {
    int idx = tid + l * 256;
    int r = idx >> 6;                  // wave-uniform (w + 4l)
    int c = (idx & 63) << 2;
    gll16(&A[(size_t)(bm + r) * HD + c], &sA[r][c]);
  }
  __syncthreads();

  float4 acc[ER];
#pragma unroll
  for (int r = 0; r < ER; ++r) acc[r] = make_float4(0.f, 0.f, 0.f, 0.f);

  const int ks = w * 64;
  kloop2<ER>(acc, &sA[0][0], HD, W + (size_t)ks * OD + cb + tx * 4, OD, 16, ks);
  reduce4<ER>(acc, pbA, pbB, w, tx);

  if (w == 0) {
    float4 bv = ld4(&bias[cb + tx * 4]);
#pragma unroll
    for (int r = 0; r < ER; ++r) {
      float4 o = make_float4(acc[r].x + bv.x, acc[r].y + bv.y,
                             acc[r].z + bv.z, acc[r].w + bv.w);
      *(float4*)&C[(size_t)(bm + r) * OD + cb + tx * 4] = o;
    }
  }
}

// ---------------- fused expert: part_k[n] = wk*relu(relu(S@W1+b1)@W2+b2) ----------------
// XCD-balanced decode: 24 half-temper units, 3 per XCD -> 2.4MB weights/XCD L2.
// grid.x = 8 * 3 * 3 * 128 = 9216; 256 thr, 4 waves k-split (64 k each), ER=8.
__global__ __launch_bounds__(256) void k_h1h2(
    int hop,
    const float* __restrict__ W1, const float* __restrict__ b1,
    const float* __restrict__ W2, const float* __restrict__ b2,
    const float* __restrict__ op_noise,
    const int* __restrict__ cnt, const int* __restrict__ gidx,
    const float* __restrict__ states, float* __restrict__ part) {
  const int bid = blockIdx.x;
  const int xcd = bid & 7;
  const int s   = bid >> 3;            // [0,1152)
  const int u   = xcd * 3 + (s % 3);   // unit [0,24)
  const int inner = s / 3;             // [0,384)
  const int k   = inner % 3;
  const int j   = inner / 3;           // [0,128)
  const int t   = u >> 1;
  const int uh  = u & 1;
  const int rb  = j * 2 + uh;          // rowblock [0,256)

  const int cntv = cnt[hop * 16 + t];
  const int r0 = rb * ER;
  if (r0 >= cntv) return;
  const int gb = (hop * TN + t) * BN_ + r0;
  const int rows = min(ER, cntv - r0);

  __shared__ __align__(16) float sA[ER][HD];   // 8KB states rows
  __shared__ __align__(16) float sH[ER][HD];   // 8KB h1
  __shared__ float4 pbA[ER][64];               // 8KB
  __shared__ float4 pbB[ER][64];               // 8KB  -> 32KB total
  const int tid = threadIdx.x;
  const int tx = tid & 63;
  const int w = tid >> 6;

  // gather active rows (wave-uniform r; tail rows stale -> discarded)
#pragma unroll
  for (int l = 0; l < 2; ++l) {
    int r = w + 4 * l;
    int c = tx << 2;
    if (r < rows)
      gll16(&states[(size_t)gidx[gb + r] * HD + c], &sA[r][c]);
  }
  __syncthreads();

  const float* Wa = W1 + (size_t)(t * KN + k) * HD * HD;
  const float* Wb = W2 + (size_t)(t * KN + k) * HD * HD;
  const int ks = w * 64;

  float4 acc[ER];
#pragma unroll
  for (int r = 0; r < ER; ++r) acc[r] = make_float4(0.f, 0.f, 0.f, 0.f);

  // ---- layer 1 ----
  kloop2<ER>(acc, &sA[0][0], HD, Wa + (size_t)ks * HD + tx * 4, HD, 16, ks);
  reduce4<ER>(acc, pbA, pbB, w, tx);

  if (w == 0) {
    float4 bv = ld4(&b1[(t * KN + k) * HD + tx * 4]);
#pragma unroll
    for (int r = 0; r < ER; ++r) {
      float4 hh;
      hh.x = fmaxf(acc[r].x + bv.x, 0.f);
      hh.y = fmaxf(acc[r].y + bv.y, 0.f);
      hh.z = fmaxf(acc[r].z + bv.z, 0.f);
      hh.w = fmaxf(acc[r].w + bv.w, 0.f);
      *(float4*)&sH[r][tx * 4] = hh;
    }
  }
  __syncthreads();

  // ---- layer 2 ----
#pragma unroll
  for (int r = 0; r < ER; ++r) acc[r] = make_float4(0.f, 0.f, 0.f, 0.f);
  kloop2<ER>(acc, &sH[0][0], HD, Wb + (size_t)ks * HD + tx * 4, HD, 16, ks);
  reduce4<ER>(acc, pbA, pbB, w, tx);

  if (w == 0) {
    float wkk;
    {
      const float* on = op_noise + (hop * TN + t) * KN;
      float x0 = on[0], x1 = on[1], x2 = on[2];
      float m = fmaxf(fmaxf(x0, x1), x2);
      float e0 = expf(x0 - m), e1 = expf(x1 - m), e2 = expf(x2 - m);
      float ek = (k == 0) ? e0 : (k == 1) ? e1 : e2;
      wkk = ek / (e0 + e1 + e2);
    }
    float4 bv = ld4(&b2[(t * KN + k) * HD + tx * 4]);
#pragma unroll
    for (int r = 0; r < ER; ++r) {
      if (r < rows) {
        int n = gidx[gb + r];
        float4 o;
        o.x = wkk * fmaxf(acc[r].x + bv.x, 0.f);
        o.y = wkk * fmaxf(acc[r].y + bv.y, 0.f);
        o.z = wkk * fmaxf(acc[r].z + bv.z, 0.f);
        o.w = wkk * fmaxf(acc[r].w + bv.w, 0.f);
        *(float4*)&part[((size_t)k * BN_ + n) * HD + tx * 4] = o;
      }
    }
  }
}

// ---------------- combine partials + routing + Gumbel argmax + regroup ----------------
__global__ __launch_bounds__(256) void k_comb(
    int hop,
    const float* __restrict__ Wr, const float* __restrict__ br,
    const float* __restrict__ route_u,
    int* __restrict__ cnt, int* __restrict__ gidx,
    const float* __restrict__ part,
    float* __restrict__ states) {
  const int t  = blockIdx.x % TN;
  const int rb = blockIdx.x / TN;
  const int cntv = cnt[hop * 16 + t];
  const int r0 = rb * CR;
  if (r0 >= cntv) return;
  const int gb = (hop * TN + t) * BN_ + r0;
  const int rows = min(CR, cntv - r0);

  __shared__ float sO[CR][HD + 4];
  __shared__ float sWr[HD * TP1];
  __shared__ float sL[CR][16];
  __shared__ int   sN[CR];

  const int tid = threadIdx.x;
  if (tid < CR && tid < rows) sN[tid] = gidx[gb + tid];

#pragma unroll
  for (int l = 0; l < 4; ++l) {
    int idx = tid + l * 256;
    int r = idx >> 6;
    int c = (idx & 63) << 2;
    if (r < rows) {
      int n = gidx[gb + r];
      size_t p = (size_t)n * HD + c;
      float4 a = ld4(&part[p]);
      float4 b = ld4(&part[(size_t)BN_ * HD + p]);
      float4 cc = ld4(&part[(size_t)2 * BN_ * HD + p]);
      float4 v = make_float4(a.x + b.x + cc.x, a.y + b.y + cc.y,
                             a.z + b.z + cc.z, a.w + b.w + cc.w);
      *(float4*)&sO[r][c] = v;
      *(float4*)&states[(size_t)n * HD + c] = v;
    }
  }
  for (int i = tid; i < HD * TP1; i += 256)
    sWr[i] = Wr[(size_t)t * HD * TP1 + i];
  __syncthreads();

  int r = tid >> 4, g = tid & 15;
  if (r < rows && g < TP1) {
    float a = br[t * TP1 + g];
#pragma unroll 8
    for (int f = 0; f < HD; ++f) a = fmaf(sO[r][f], sWr[f * TP1 + g], a);
    float u = route_u[((size_t)hop * BN_ + sN[r]) * TP1 + g];
    float gb_ = -logf(-logf(u + 1e-9f) + 1e-9f);
    sL[r][g] = a + gb_;
  }
  __syncthreads();

  if (tid < rows) {
    float best = sL[tid][0];
    int bj = 0;
#pragma unroll
    for (int gg = 1; gg < TP1; ++gg) {
      float v = sL[tid][gg];
      if (v > best) { best = v; bj = gg; }
    }
    if (hop + 1 < NHOPS && bj != TN) {
      int n = sN[tid];
      int slot = atomicAdd(&cnt[(hop + 1) * 16 + bj], 1);
      gidx[((hop + 1) * TN + bj) * BN_ + slot] = n;
    }
  }
}

// ---------------- launcher ----------------
extern "C" void kernel_launch(void* const* d_in, const int* in_sizes, int n_in,
                              void* d_out, int out_size, void* d_ws, size_t ws_size,
                              hipStream_t stream) {
  const float* x        = (const float*)d_in[0];
  const int*   init_t   = (const int*)d_in[1];
  const float* op_noise = (const float*)d_in[2];
  const float* route_u  = (const float*)d_in[3];
  const float* W_in     = (const float*)d_in[4];
  const float* b_in     = (const float*)d_in[5];
  const float* W1       = (const float*)d_in[6];
  const float* b1       = (const float*)d_in[7];
  const float* W2       = (const float*)d_in[8];
  const float* b2       = (const float*)d_in[9];
  const float* Wr       = (const float*)d_in[10];
  const float* br       = (const float*)d_in[11];
  const float* W_out    = (const float*)d_in[12];
  const float* b_out    = (const float*)d_in[13];
  float* out = (float*)d_out;

  float* states = (float*)d_ws;                       // 2MB
  float* part   = states + (size_t)BN_ * HD;          // [KN][BN_][HD] 6MB
  float* pp     = part;                               // gemm_in partials alias (4MB)
  int* cnt  = (int*)(part + (size_t)KN * BN_ * HD);   // [NHOPS][16]
  int* gidx = cnt + NHOPS * 16;                       // [NHOPS][TN][BN_]

  k_init<<<1, 1024, 0, stream>>>(init_t, cnt, gidx);

  k_gemm_in<<<dim3(BN_ / ER, 2), 256, 0, stream>>>(x, W_in, pp);
  k_cin<<<(BN_ * HD / 4) / 256, 256, 0, stream>>>(pp, b_in, states);

  for (int hop = 0; hop < NHOPS; ++hop) {
    k_h1h2<<<8 * 3 * 3 * 128, 256, 0, stream>>>(
        hop, W1, b1, W2, b2, op_noise, cnt, gidx, states, part);
    k_comb<<<TN * (BN_ / CR), 256, 0, stream>>>(
        hop, Wr, br, route_u, cnt, gidx, part, states);
  }

  k_gemm_out<<<dim3(BN_ / ER, OD / 256), 256, 0, stream>>>(states, W_out, b_out, out);
}